// Round 5
// baseline (10096.960 us; speedup 1.0000x reference)
//
#include <hip/hip_runtime.h>

// ---------------------------------------------------------------------------
// SignLLM forward: encoder -> LN/ReLU -> enc2 -> VQ -> (codebook tables for
// projector & GRU-input) -> MMD via histogram -> persistent-kernel GRU ->
// head GEMM with fused sq-err reduction -> 4 scalar losses.
// Round 5: GRU sync collapsed from 4 serial fabric round-trips per step
// (drain -> flag visible -> poll -> data load; measured 10.3us/step in r1/r2/
// r4) to ~1: the epoch tag is EMBEDDED in each 8-byte h unit (atomic u64 =
// {2 bf16, u32 tag}). Producers fire-and-forget; consumers poll the data
// itself and self-validate. No flags, no vm_drain, no hot lines.
// ---------------------------------------------------------------------------

typedef __attribute__((ext_vector_type(4))) float  f32x4;
typedef __attribute__((ext_vector_type(8))) short  s16x8;
typedef __attribute__((ext_vector_type(4))) short  s16x4;
typedef __attribute__((ext_vector_type(8))) __bf16 bf16x8;
typedef __attribute__((ext_vector_type(4))) unsigned int u32x4;
typedef unsigned long long u64;
typedef unsigned int       u32;

__device__ __forceinline__ short f2bf(float f) {
  __bf16 h = (__bf16)f;
  return __builtin_bit_cast(short, h);
}
__device__ __forceinline__ float bf2f(short s) {
  return (float)__builtin_bit_cast(__bf16, s);
}
__device__ __forceinline__ f32x4 mfma16(s16x8 a, s16x8 b, f32x4 c) {
  return __builtin_amdgcn_mfma_f32_16x16x32_bf16(
      __builtin_bit_cast(bf16x8, a), __builtin_bit_cast(bf16x8, b), c, 0, 0, 0);
}

// ---------------------------------------------------------------------------
// Generic bf16 MFMA GEMM: C[M,N] = A[M,K] @ B[K,N] + bias, tile 128x128, BK=64
// EPI: 0 = store f32, 1 = store bf16, 2 = relu+store bf16,
//      3 = no store; accumulate sum((C - Xref)^2) into accum (head loss)
// ---------------------------------------------------------------------------
template<bool AF32, int EPI>
__global__ __launch_bounds__(256)
void gemm_k(const void* __restrict__ Ap, const float* __restrict__ Bp,
            const float* __restrict__ bias, void* __restrict__ Cp,
            const float* __restrict__ Xref, float* __restrict__ accum,
            int M, int N, int K)
{
  __shared__ short As[128][72];   // row-major [m][k], padded
  __shared__ short Bs[128][72];   // col-major [n][k], padded
  const int tid  = threadIdx.x;
  const long bm  = (long)blockIdx.x * 128;
  const long bn  = (long)blockIdx.y * 128;
  const int wave = tid >> 6, lane = tid & 63;
  const int wm = (wave >> 1) * 64, wn = (wave & 1) * 64;
  const int l16 = lane & 15, quad = lane >> 4;

  f32x4 acc[4][4];
#pragma unroll
  for (int i = 0; i < 4; ++i)
#pragma unroll
    for (int j = 0; j < 4; ++j) acc[i][j] = (f32x4){0.f, 0.f, 0.f, 0.f};

  const int atc = tid & 15, atr = tid >> 4;   // A staging: 16 cols x 16 rows
  const int btc = tid & 31, btr = tid >> 5;   // B staging: 32 cols x 8 rows

  for (int kt = 0; kt < K; kt += 64) {
#pragma unroll
    for (int p = 0; p < 8; ++p) {
      int r = p * 16 + atr;
      if (AF32) {
        const float* src = (const float*)Ap + (bm + r) * (long)K + kt + atc * 4;
        f32x4 v = *(const f32x4*)src;
        s16x4 s;
        s.x = f2bf(v.x); s.y = f2bf(v.y); s.z = f2bf(v.z); s.w = f2bf(v.w);
        *(s16x4*)&As[r][atc * 4] = s;
      } else {
        const short* src = (const short*)Ap + (bm + r) * (long)K + kt + atc * 4;
        *(s16x4*)&As[r][atc * 4] = *(const s16x4*)src;
      }
    }
#pragma unroll
    for (int p = 0; p < 8; ++p) {
      int kk = p * 8 + btr;
      const float* brow = Bp + (long)(kt + kk) * N + bn + btc;
#pragma unroll
      for (int j = 0; j < 4; ++j) Bs[btc + 32 * j][kk] = f2bf(brow[32 * j]);
    }
    __syncthreads();
#pragma unroll
    for (int kk = 0; kk < 64; kk += 32) {
      s16x8 af[4], bf[4];
#pragma unroll
      for (int i = 0; i < 4; ++i)
        af[i] = *(const s16x8*)&As[wm + i * 16 + l16][kk + quad * 8];
#pragma unroll
      for (int j = 0; j < 4; ++j)
        bf[j] = *(const s16x8*)&Bs[wn + j * 16 + l16][kk + quad * 8];
#pragma unroll
      for (int i = 0; i < 4; ++i)
#pragma unroll
        for (int j = 0; j < 4; ++j) acc[i][j] = mfma16(af[i], bf[j], acc[i][j]);
    }
    __syncthreads();
  }

  if (EPI == 3) {
    float ls = 0.f;
#pragma unroll
    for (int i = 0; i < 4; ++i)
#pragma unroll
      for (int j = 0; j < 4; ++j) {
        long col = bn + wn + j * 16 + l16;
        float bv = bias[col];
#pragma unroll
        for (int r = 0; r < 4; ++r) {
          long row = bm + wm + i * 16 + quad * 4 + r;
          float v = acc[i][j][r] + bv;
          float d = v - Xref[row * N + col];
          ls += d * d;
        }
      }
#pragma unroll
    for (int off = 32; off > 0; off >>= 1) ls += __shfl_xor(ls, off, 64);
    if (lane == 0) atomicAdd(accum, ls);
  } else {
#pragma unroll
    for (int i = 0; i < 4; ++i)
#pragma unroll
      for (int j = 0; j < 4; ++j) {
        long col = bn + wn + j * 16 + l16;
        float bv = bias[col];
#pragma unroll
        for (int r = 0; r < 4; ++r) {
          long row = bm + wm + i * 16 + quad * 4 + r;
          float v = acc[i][j][r] + bv;
          if (EPI == 2) v = fmaxf(v, 0.f);
          if (EPI == 0) ((float*)Cp)[row * N + col] = v;
          else          ((short*)Cp)[row * N + col] = f2bf(v);
        }
      }
  }
}

// ---------------------------------------------------------------------------
// LayerNorm(512) + ReLU, fp32 in -> bf16 out. One wave per row.
// ---------------------------------------------------------------------------
__global__ __launch_bounds__(256)
void ln_relu_k(const float* __restrict__ hp, const float* __restrict__ g,
               const float* __restrict__ b, short* __restrict__ out)
{
  const int wave = threadIdx.x >> 6, lane = threadIdx.x & 63;
  const long row = (long)blockIdx.x * 4 + wave;
  const float* hr = hp + row * 512;
  const int c0 = lane * 4, c1 = 256 + lane * 4;
  f32x4 v0 = *(const f32x4*)(hr + c0);
  f32x4 v1 = *(const f32x4*)(hr + c1);
  float s  = v0.x + v0.y + v0.z + v0.w + v1.x + v1.y + v1.z + v1.w;
  float ss = v0.x*v0.x + v0.y*v0.y + v0.z*v0.z + v0.w*v0.w
           + v1.x*v1.x + v1.y*v1.y + v1.z*v1.z + v1.w*v1.w;
#pragma unroll
  for (int off = 32; off > 0; off >>= 1) {
    s  += __shfl_xor(s, off, 64);
    ss += __shfl_xor(ss, off, 64);
  }
  float mu  = s * (1.f / 512.f);
  float var = ss * (1.f / 512.f) - mu * mu;
  float rs  = rsqrtf(var + 1e-5f);
  f32x4 g0 = *(const f32x4*)(g + c0), bb0 = *(const f32x4*)(b + c0);
  f32x4 g1 = *(const f32x4*)(g + c1), bb1 = *(const f32x4*)(b + c1);
  s16x4 o0, o1;
#pragma unroll
  for (int e = 0; e < 4; ++e) {
    o0[e] = f2bf(fmaxf((v0[e] - mu) * rs * g0[e] + bb0[e], 0.f));
    o1[e] = f2bf(fmaxf((v1[e] - mu) * rs * g1[e] + bb1[e], 0.f));
  }
  *(s16x4*)(out + row * 512 + c0) = o0;
  *(s16x4*)(out + row * 512 + c1) = o1;
}

// ---------------------------------------------------------------------------
// Codebook prep: cbT[k][n] = codebook[n][k] (fp32), cbBias[n] = -0.5*||c_n||^2
// ---------------------------------------------------------------------------
__global__ __launch_bounds__(256)
void prep_cb_k(const float* __restrict__ cb, float* __restrict__ cbT,
               float* __restrict__ cbBias)
{
  __shared__ float red[256];
  const int r = blockIdx.x, tid = threadIdx.x;
  const float* row = cb + (long)r * 1024;
  float ss = 0.f;
  for (int c = tid; c < 1024; c += 256) {
    float v = row[c];
    cbT[(long)c * 256 + r] = v;
    ss += v * v;
  }
  red[tid] = ss; __syncthreads();
  for (int st = 128; st > 0; st >>= 1) {
    if (tid < st) red[tid] += red[tid + st];
    __syncthreads();
  }
  if (tid == 0) cbBias[r] = -0.5f * red[0];
}

// ---------------------------------------------------------------------------
// VQ: per-row argmax of scores (=f.c - .5||c||^2) + e_latent accumulation
// ---------------------------------------------------------------------------
__global__ __launch_bounds__(256)
void vq_k(const float* __restrict__ sc, const short* __restrict__ feat,
          int* __restrict__ idxp, float* __restrict__ e_acc)
{
  __shared__ float ep[4];
  const int wave = threadIdx.x >> 6, lane = threadIdx.x & 63;
  const long row = (long)blockIdx.x * 4 + wave;
  f32x4 s = *(const f32x4*)(sc + row * 256 + lane * 4);
  float best = s.x; int bi = lane * 4;
  if (s.y > best) { best = s.y; bi = lane * 4 + 1; }
  if (s.z > best) { best = s.z; bi = lane * 4 + 2; }
  if (s.w > best) { best = s.w; bi = lane * 4 + 3; }
#pragma unroll
  for (int off = 32; off > 0; off >>= 1) {
    float ov = __shfl_xor(best, off, 64);
    int   oi = __shfl_xor(bi, off, 64);
    if (ov > best || (ov == best && oi < bi)) { best = ov; bi = oi; }
  }
  const short* fr = feat + row * 1024;
  float sq = 0.f;
#pragma unroll
  for (int p = 0; p < 2; ++p) {
    s16x8 v = *(const s16x8*)(fr + p * 512 + lane * 8);
#pragma unroll
    for (int e = 0; e < 8; ++e) { float f = bf2f(v[e]); sq += f * f; }
  }
#pragma unroll
  for (int off = 32; off > 0; off >>= 1) sq += __shfl_xor(sq, off, 64);
  if (lane == 0) { idxp[row] = bi; ep[wave] = sq - 2.f * best; }
  __syncthreads();
  if (threadIdx.x == 0) atomicAdd(e_acc, ep[0] + ep[1] + ep[2] + ep[3]);
}

// ---------------------------------------------------------------------------
// Per-batch code histogram -> xm[b,:] = (hist/512) @ aligned_codes
// ---------------------------------------------------------------------------
__global__ __launch_bounds__(256)
void hist_xm_k(const int* __restrict__ idxp, const float* __restrict__ AC,
               float* __restrict__ xm)
{
  __shared__ int   hist[256];
  __shared__ float hf[256];
  const int b = blockIdx.x, tid = threadIdx.x;
  hist[tid] = 0; __syncthreads();
  for (int t = tid; t < 512; t += 256) atomicAdd(&hist[idxp[b * 512 + t]], 1);
  __syncthreads();
  hf[tid] = (float)hist[tid] * (1.f / 512.f);
  __syncthreads();
  for (int d = tid; d < 1024; d += 256) {
    float a = 0.f;
    for (int k = 0; k < 256; ++k) a += hf[k] * AC[(long)k * 1024 + d];
    xm[(long)b * 1024 + d] = a;
  }
}

// ---------------------------------------------------------------------------
// MMD: one block, 1024 threads = 32x32 pairs; xm staged in LDS (padded)
// ---------------------------------------------------------------------------
__global__ __launch_bounds__(1024)
void mmd_k(const float* __restrict__ xm, const float* __restrict__ prior,
           float* __restrict__ mmd_out)
{
  extern __shared__ float xs[];   // [32][1028]
  __shared__ float red[48];
  const int tid = threadIdx.x;
  for (int i = tid; i < 32 * 1024; i += 1024)
    xs[(i >> 10) * 1028 + (i & 1023)] = xm[i];
  __syncthreads();
  const int i = tid >> 5, j = tid & 31;
  const float* xi = xs + i * 1028;
  const float* xj = xs + j * 1028;
  const float* pi = prior + (long)i * 1024;
  const float* pj = prior + (long)j * 1024;
  float dxx = 0.f, dyy = 0.f, dxy = 0.f;
  for (int d = 0; d < 1024; d += 4) {
    f32x4 a = *(const f32x4*)(xi + d);
    f32x4 b = *(const f32x4*)(xj + d);
    f32x4 p = *(const f32x4*)(pi + d);
    f32x4 q = *(const f32x4*)(pj + d);
#pragma unroll
    for (int e = 0; e < 4; ++e) {
      float t1 = a[e] - b[e]; dxx += t1 * t1;
      float t2 = p[e] - q[e]; dyy += t2 * t2;
      float t3 = a[e] - q[e]; dxy += t3 * t3;
    }
  }
  float kxx = __expf(-dxx * (1.f / 1024.f));
  float kyy = __expf(-dyy * (1.f / 1024.f));
  float kxy = __expf(-dxy * (1.f / 1024.f));
  const int wv = tid >> 6, lane = tid & 63;
#pragma unroll
  for (int off = 32; off > 0; off >>= 1) {
    kxx += __shfl_xor(kxx, off, 64);
    kyy += __shfl_xor(kyy, off, 64);
    kxy += __shfl_xor(kxy, off, 64);
  }
  if (lane == 0) { red[wv] = kxx; red[16 + wv] = kyy; red[32 + wv] = kxy; }
  __syncthreads();
  if (tid == 0) {
    float sxx = 0.f, syy = 0.f, sxy = 0.f;
    for (int w = 0; w < 16; ++w) {
      sxx += red[w]; syy += red[16 + w]; sxy += red[32 + w];
    }
    mmd_out[0] = (sxx + syy - 2.f * sxy) * (1.f / 1024.f);
  }
}

// ---------------------------------------------------------------------------
// Persistent GRU, round 5. 64 WGs x 128 thr. WG g owns hidden dims
// [g*16, g*16+16). h exchanged via hx[slot=t&1][row 32][colpair 512] of
// atomic u64 units {lo16=h[2cp], hi16=h[2cp+1], hi32=step tag}. Producers:
// fire-and-forget relaxed agent stores (no drain/flags). Consumers: batch
// 128 atomic u64 loads, min-reduce embedded tags, retry if any < t-1
// (stale value can only be t-3 or init -1; double-buffer + all-to-all
// dependency proves no overwrite hazard). ctx written separately (plain
// cached stores; kernel-boundary flush covers the head GEMM).
// ---------------------------------------------------------------------------
__global__ __launch_bounds__(128, 1)
void gru_k(const float* __restrict__ Whh, const float* __restrict__ bhh,
           const float* __restrict__ cgx, const int* __restrict__ idxp,
           u64* __restrict__ hx, u32* __restrict__ ctxw)
{
  extern __shared__ short Bsl[];   // [48][1034] bf16 + 2x[16 cols][20] scratch
  short* scr = Bsl + 48 * 1034;
  const int tid = threadIdx.x, g = blockIdx.x;
  const int wave = tid >> 6, lane = tid & 63;
  const int l16 = lane & 15, quad = lane >> 4;

  // stage Whh slice: local col c = gate*16+dl -> global col gate*1024+g*16+dl
  for (int i = tid; i < 48 * 1024; i += 128) {
    int c = i % 48, k = i / 48;
    int gate = c >> 4, dl = c & 15;
    Bsl[c * 1034 + k] = f2bf(Whh[(long)k * 3072 + gate * 1024 + g * 16 + dl]);
  }
  const int dcol = g * 16 + l16;
  const float bhr = bhh[dcol], bhz = bhh[dcol + 1024], bhn = bhh[dcol + 2048];
  const short* b0 = &Bsl[l16 * 1034 + quad * 8];
  const short* b1 = b0 + 16 * 1034;
  const short* b2 = b0 + 32 * 1034;
  short* sw = scr + wave * 320;          // [16 cols][20] this wave's scratch
  float hreg[4] = {0.f, 0.f, 0.f, 0.f};
  int brow[4];
#pragma unroll
  for (int r = 0; r < 4; ++r) brow[r] = wave * 16 + quad * 4 + r;
  const int myrow = wave * 16 + l16;     // A row this lane feeds to MFMA
  __syncthreads();   // Bsl staged by both waves

  // preload gx for t=0 (cached; L2 stays valid the whole loop)
  float xr[4], xz[4], xn[4];
#pragma unroll
  for (int r = 0; r < 4; ++r) {
    int code = idxp[brow[r] * 512];
    const float* gp = cgx + (long)code * 3072 + dcol;
    xr[r] = gp[0]; xz[r] = gp[1024]; xn[r] = gp[2048];
  }

  for (int t = 0; t < 512; ++t) {
    f32x4 ar_ = {0.f,0.f,0.f,0.f}, az = ar_, an = ar_;
    if (t > 0) {
      // self-validating batch read of h(t-1): 128 u64 units for row `myrow`
      const u64* hb = hx + ((long)(((t - 1) & 1) * 32 + myrow)) * 512 + quad * 4;
      u64 A2[128];
      const int tmin = t - 1;
      int att = 0, ok;
      do {
        if (att++) __builtin_amdgcn_s_sleep(1);
#pragma unroll
        for (int ks = 0; ks < 32; ++ks)
#pragma unroll
          for (int i = 0; i < 4; ++i)
            A2[ks * 4 + i] = __hip_atomic_load(hb + ks * 16 + i,
                                 __ATOMIC_RELAXED, __HIP_MEMORY_SCOPE_AGENT);
        int mn = 0x7fffffff;
#pragma unroll
        for (int u = 0; u < 128; ++u) {
          int tg = (int)(u32)(A2[u] >> 32);
          mn = tg < mn ? tg : mn;
        }
        ok = __all(mn >= tmin);
      } while (!ok);
      // gh = h_{t-1} @ Whh_slice (A from unit low-dwords, B from LDS)
#pragma unroll
      for (int ks = 0; ks < 32; ++ks) {
        u32x4 aw;
        aw.x = (u32)A2[ks * 4 + 0]; aw.y = (u32)A2[ks * 4 + 1];
        aw.z = (u32)A2[ks * 4 + 2]; aw.w = (u32)A2[ks * 4 + 3];
        s16x8 a8 = __builtin_bit_cast(s16x8, aw);
        ar_ = mfma16(a8, *(const s16x8*)(b0 + ks * 32), ar_);
        az  = mfma16(a8, *(const s16x8*)(b1 + ks * 32), az);
        an  = mfma16(a8, *(const s16x8*)(b2 + ks * 32), an);
      }
    }
    // gates
#pragma unroll
    for (int r = 0; r < 4; ++r) {
      float rr = 1.f / (1.f + __expf(-(xr[r] + ar_[r] + bhr)));
      float zz = 1.f / (1.f + __expf(-(xz[r] + az[r] + bhz)));
      float u  = xn[r] + rr * (an[r] + bhn);
      float e  = __expf(-2.f * u);
      float nn = (1.f - e) / (1.f + e);
      hreg[r]  = (1.f - zz) * nn + zz * hreg[r];
    }
    // publish h_t ASAP: LDS micro-transpose (per-wave, no s_barrier needed)
    // write: lane (quad,l16) -> 4 rows at col l16: scratch[col l16][quad*4+r]
    s16x4 hv;
    hv.x = f2bf(hreg[0]); hv.y = f2bf(hreg[1]);
    hv.z = f2bf(hreg[2]); hv.w = f2bf(hreg[3]);
    *(s16x4*)(sw + l16 * 20 + quad * 4) = hv;   // byte 40*l16+8*quad, aligned
    asm volatile("s_waitcnt lgkmcnt(0)" ::: "memory");
    __builtin_amdgcn_wave_barrier();
    // read 2 units/lane: unit u=(row_loc=u&15, cp=u>>4) = cols {2cp,2cp+1}
#pragma unroll
    for (int s = 0; s < 2; ++s) {
      int u = lane + 64 * s;
      int row_loc = u & 15, cp = u >> 4;
      u32 v0 = (unsigned short)sw[(2 * cp) * 20 + row_loc];
      u32 v1 = (unsigned short)sw[(2 * cp + 1) * 20 + row_loc];
      u32 dat = v0 | (v1 << 16);
      u64 unit = (u64)dat | ((u64)(u32)t << 32);
      int rg = wave * 16 + row_loc;
      __hip_atomic_store(hx + ((long)((t & 1) * 32 + rg)) * 512 + g * 8 + cp,
                         unit, __ATOMIC_RELAXED, __HIP_MEMORY_SCOPE_AGENT);
      ctxw[((long)rg * 512 + t) * 512 + g * 8 + cp] = dat;   // plain cached
    }
    // prefetch gx for t+1 (cached loads; overlap with next step's poll)
    int tn = (t + 1 < 512) ? t + 1 : 0;
#pragma unroll
    for (int r = 0; r < 4; ++r) {
      int code = idxp[brow[r] * 512 + tn];
      const float* gp = cgx + (long)code * 3072 + dcol;
      xr[r] = gp[0]; xz[r] = gp[1024]; xn[r] = gp[2048];
    }
  }
}

// ---------------------------------------------------------------------------
__global__ void fin_k(const float* __restrict__ scal, float* __restrict__ out)
{
  float recon = scal[3] * (1.f / 16777216.f);
  float vq    = 1.25f * scal[2] * (1.f / 16777216.f);
  float mmd   = scal[4];
  out[0] = recon;
  out[1] = vq;
  out[2] = mmd;
  out[3] = recon + vq + 0.5f * mmd;
}

// ---------------------------------------------------------------------------
extern "C" void kernel_launch(void* const* d_in, const int* in_sizes, int n_in,
                              void* d_out, int out_size, void* d_ws, size_t ws_size,
                              hipStream_t stream)
{
  const float* x     = (const float*)d_in[0];
  const float* prior = (const float*)d_in[1];
  const float* encW1 = (const float*)d_in[2];
  const float* encb1 = (const float*)d_in[3];
  const float* lng   = (const float*)d_in[4];
  const float* lnb   = (const float*)d_in[5];
  const float* encW2 = (const float*)d_in[6];
  const float* encb2 = (const float*)d_in[7];
  const float* cb    = (const float*)d_in[8];
  const float* pW1   = (const float*)d_in[9];
  const float* pb1   = (const float*)d_in[10];
  const float* pW2   = (const float*)d_in[11];
  const float* pb2   = (const float*)d_in[12];
  const float* Wih   = (const float*)d_in[13];
  const float* Whh   = (const float*)d_in[14];
  const float* bih   = (const float*)d_in[15];
  const float* bhh   = (const float*)d_in[16];
  const float* headW = (const float*)d_in[17];
  const float* headb = (const float*)d_in[18];

  // workspace layout (total 89,654,528 B, same as previous rounds)
  char* ws = (char*)d_ws;
  if (ws_size < 89654528) return;
  float* h_pre  = (float*)(ws + 0);           // 32 MB (scores alias)
  float* scores = h_pre;
  u64*   hx     = (u64*)(ws + 0);             // 256 KB (after vq_k): h units
  short* h1     = (short*)(ws + 33554432);    // 16 MB
  short* feat   = (short*)(ws + 50331648);    // 32 MB (ctx alias after VQ)
  u32*   ctxw   = (u32*)feat;
  short* ctxr   = feat;
  float* cgx    = (float*)(ws + 83886080);    // 3 MB  code_gx = cb@Wih+bih
  float* AC     = (float*)(ws + 87031808);    // 1 MB  aligned codes
  float* cbT    = (float*)(ws + 88080384);    // 1 MB  codebook^T f32
  short* ch     = (short*)(ws + 89128960);    // 256 KB codes hidden (bf16)
  float* xm     = (float*)(ws + 89391104);    // 128 KB
  int*   idxp   = (int*)  (ws + 89522176);    // 64 KB
  float* scal   = (float*)(ws + 89653248);    // 256 B scalars
  float* e_acc  = scal + 2;
  float* r_acc  = scal + 3;
  float* mmdv   = scal + 4;
  float* cbBias = (float*)(ws + 89653504);    // 1 KB

  // zero loss accumulators (ws is poisoned 0xAA each launch)
  hipMemsetAsync(scal, 0, 256, stream);

  dim3 blk(256);
  prep_cb_k<<<256, blk, 0, stream>>>(cb, cbT, cbBias);
  // encoder layer 1: x @ W1 + b1 -> h_pre (f32)
  gemm_k<true, 0><<<dim3(128, 4), blk, 0, stream>>>(
      x, encW1, encb1, h_pre, nullptr, nullptr, 16384, 512, 1024);
  ln_relu_k<<<4096, blk, 0, stream>>>(h_pre, lng, lnb, h1);
  // encoder layer 2: h1 @ W2 + b2 -> feat (bf16)
  gemm_k<false, 1><<<dim3(128, 8), blk, 0, stream>>>(
      h1, encW2, encb2, feat, nullptr, nullptr, 16384, 1024, 512);
  // VQ scores: feat @ cbT - 0.5||c||^2 -> scores (f32, aliases h_pre)
  gemm_k<false, 0><<<dim3(128, 2), blk, 0, stream>>>(
      feat, cbT, cbBias, scores, nullptr, nullptr, 16384, 256, 1024);
  vq_k<<<4096, blk, 0, stream>>>(scores, feat, idxp, e_acc);
  // scores region dead -> hx lives there; init tags to -1 (0xFF bytes)
  hipMemsetAsync(ws, 0xFF, 262144, stream);
  // per-code tables: projector hidden (relu, bf16), aligned codes, gru gx
  gemm_k<true, 2><<<dim3(2, 4), blk, 0, stream>>>(
      cb, pW1, pb1, ch, nullptr, nullptr, 256, 512, 1024);
  gemm_k<false, 0><<<dim3(2, 8), blk, 0, stream>>>(
      ch, pW2, pb2, AC, nullptr, nullptr, 256, 1024, 512);
  gemm_k<true, 0><<<dim3(2, 24), blk, 0, stream>>>(
      cb, Wih, bih, cgx, nullptr, nullptr, 256, 3072, 1024);
  // MMD path
  hist_xm_k<<<32, blk, 0, stream>>>(idxp, AC, xm);
  mmd_k<<<1, 1024, 32 * 1028 * 4, stream>>>(xm, prior, mmdv);
  // persistent GRU (tag-embedded h exchange; writes ctx for the head GEMM)
  gru_k<<<64, 128, (48 * 1034 + 2 * 320) * 2, stream>>>(
      Whh, bhh, cgx, idxp, hx, ctxw);
  // head GEMM + fused recon sq-err reduction
  gemm_k<false, 3><<<dim3(128, 8), blk, 0, stream>>>(
      ctxr, headW, headb, nullptr, x, r_acc, 16384, 1024, 1024);
  fin_k<<<1, 1, 0, stream>>>(scal, (float*)d_out);
}

// Round 6
// 5757.306 us; speedup vs baseline: 1.7538x; 1.7538x over previous
//
#include <hip/hip_runtime.h>

// ---------------------------------------------------------------------------
// SignLLM forward. Round 6: GRU h exchange rides the CACHED read path.
// Evidence r1-r5: per-step time tracks uncached-path request count (~400GB/s
// service ceiling); cached path does TB/s. So: readers use plain nontemporal
// b128 loads of virgin ctx[.,t-1,.] lines (read-once => no staleness; publish
// is sc1 write-through to LLC; XCD L2 multicasts fills to its 8 WGs).
// Publish: LDS micro-transpose -> b128 sc1 stores (4x fewer store requests
// than r4), no separate hx buffer. Flags protocol unchanged from r4.
// ---------------------------------------------------------------------------

typedef __attribute__((ext_vector_type(4))) float  f32x4;
typedef __attribute__((ext_vector_type(8))) short  s16x8;
typedef __attribute__((ext_vector_type(4))) short  s16x4;
typedef __attribute__((ext_vector_type(8))) __bf16 bf16x8;
typedef __attribute__((ext_vector_type(4))) unsigned int u32x4;
typedef unsigned long long u64;
typedef unsigned int       u32;

__device__ __forceinline__ short f2bf(float f) {
  __bf16 h = (__bf16)f;
  return __builtin_bit_cast(short, h);
}
__device__ __forceinline__ float bf2f(short s) {
  return (float)__builtin_bit_cast(__bf16, s);
}
__device__ __forceinline__ f32x4 mfma16(s16x8 a, s16x8 b, f32x4 c) {
  return __builtin_amdgcn_mfma_f32_16x16x32_bf16(
      __builtin_bit_cast(bf16x8, a), __builtin_bit_cast(bf16x8, b), c, 0, 0, 0);
}
__device__ __forceinline__ void vm_drain() {
  asm volatile("s_waitcnt vmcnt(0)" ::: "memory");
}
// uncached 16B store straight to LLC (coherence point) — no L1/L2 allocate
__device__ __forceinline__ void st_uc128(u32* p, u32x4 v) {
  asm volatile("global_store_dwordx4 %0, %1, off sc0 sc1"
               :: "v"(p), "v"(v) : "memory");
}

// ---------------------------------------------------------------------------
// Generic bf16 MFMA GEMM: C[M,N] = A[M,K] @ B[K,N] + bias, tile 128x128, BK=64
// EPI: 0 = store f32, 1 = store bf16, 2 = relu+store bf16,
//      3 = no store; accumulate sum((C - Xref)^2) into accum (head loss)
// ---------------------------------------------------------------------------
template<bool AF32, int EPI>
__global__ __launch_bounds__(256)
void gemm_k(const void* __restrict__ Ap, const float* __restrict__ Bp,
            const float* __restrict__ bias, void* __restrict__ Cp,
            const float* __restrict__ Xref, float* __restrict__ accum,
            int M, int N, int K)
{
  __shared__ short As[128][72];   // row-major [m][k], padded
  __shared__ short Bs[128][72];   // col-major [n][k], padded
  const int tid  = threadIdx.x;
  const long bm  = (long)blockIdx.x * 128;
  const long bn  = (long)blockIdx.y * 128;
  const int wave = tid >> 6, lane = tid & 63;
  const int wm = (wave >> 1) * 64, wn = (wave & 1) * 64;
  const int l16 = lane & 15, quad = lane >> 4;

  f32x4 acc[4][4];
#pragma unroll
  for (int i = 0; i < 4; ++i)
#pragma unroll
    for (int j = 0; j < 4; ++j) acc[i][j] = (f32x4){0.f, 0.f, 0.f, 0.f};

  const int atc = tid & 15, atr = tid >> 4;   // A staging: 16 cols x 16 rows
  const int btc = tid & 31, btr = tid >> 5;   // B staging: 32 cols x 8 rows

  for (int kt = 0; kt < K; kt += 64) {
#pragma unroll
    for (int p = 0; p < 8; ++p) {
      int r = p * 16 + atr;
      if (AF32) {
        const float* src = (const float*)Ap + (bm + r) * (long)K + kt + atc * 4;
        f32x4 v = *(const f32x4*)src;
        s16x4 s;
        s.x = f2bf(v.x); s.y = f2bf(v.y); s.z = f2bf(v.z); s.w = f2bf(v.w);
        *(s16x4*)&As[r][atc * 4] = s;
      } else {
        const short* src = (const short*)Ap + (bm + r) * (long)K + kt + atc * 4;
        *(s16x4*)&As[r][atc * 4] = *(const s16x4*)src;
      }
    }
#pragma unroll
    for (int p = 0; p < 8; ++p) {
      int kk = p * 8 + btr;
      const float* brow = Bp + (long)(kt + kk) * N + bn + btc;
#pragma unroll
      for (int j = 0; j < 4; ++j) Bs[btc + 32 * j][kk] = f2bf(brow[32 * j]);
    }
    __syncthreads();
#pragma unroll
    for (int kk = 0; kk < 64; kk += 32) {
      s16x8 af[4], bf[4];
#pragma unroll
      for (int i = 0; i < 4; ++i)
        af[i] = *(const s16x8*)&As[wm + i * 16 + l16][kk + quad * 8];
#pragma unroll
      for (int j = 0; j < 4; ++j)
        bf[j] = *(const s16x8*)&Bs[wn + j * 16 + l16][kk + quad * 8];
#pragma unroll
      for (int i = 0; i < 4; ++i)
#pragma unroll
        for (int j = 0; j < 4; ++j) acc[i][j] = mfma16(af[i], bf[j], acc[i][j]);
    }
    __syncthreads();
  }

  if (EPI == 3) {
    float ls = 0.f;
#pragma unroll
    for (int i = 0; i < 4; ++i)
#pragma unroll
      for (int j = 0; j < 4; ++j) {
        long col = bn + wn + j * 16 + l16;
        float bv = bias[col];
#pragma unroll
        for (int r = 0; r < 4; ++r) {
          long row = bm + wm + i * 16 + quad * 4 + r;
          float v = acc[i][j][r] + bv;
          float d = v - Xref[row * N + col];
          ls += d * d;
        }
      }
#pragma unroll
    for (int off = 32; off > 0; off >>= 1) ls += __shfl_xor(ls, off, 64);
    if (lane == 0) atomicAdd(accum, ls);
  } else {
#pragma unroll
    for (int i = 0; i < 4; ++i)
#pragma unroll
      for (int j = 0; j < 4; ++j) {
        long col = bn + wn + j * 16 + l16;
        float bv = bias[col];
#pragma unroll
        for (int r = 0; r < 4; ++r) {
          long row = bm + wm + i * 16 + quad * 4 + r;
          float v = acc[i][j][r] + bv;
          if (EPI == 2) v = fmaxf(v, 0.f);
          if (EPI == 0) ((float*)Cp)[row * N + col] = v;
          else          ((short*)Cp)[row * N + col] = f2bf(v);
        }
      }
  }
}

// ---------------------------------------------------------------------------
// LayerNorm(512) + ReLU, fp32 in -> bf16 out. One wave per row.
// ---------------------------------------------------------------------------
__global__ __launch_bounds__(256)
void ln_relu_k(const float* __restrict__ hp, const float* __restrict__ g,
               const float* __restrict__ b, short* __restrict__ out)
{
  const int wave = threadIdx.x >> 6, lane = threadIdx.x & 63;
  const long row = (long)blockIdx.x * 4 + wave;
  const float* hr = hp + row * 512;
  const int c0 = lane * 4, c1 = 256 + lane * 4;
  f32x4 v0 = *(const f32x4*)(hr + c0);
  f32x4 v1 = *(const f32x4*)(hr + c1);
  float s  = v0.x + v0.y + v0.z + v0.w + v1.x + v1.y + v1.z + v1.w;
  float ss = v0.x*v0.x + v0.y*v0.y + v0.z*v0.z + v0.w*v0.w
           + v1.x*v1.x + v1.y*v1.y + v1.z*v1.z + v1.w*v1.w;
#pragma unroll
  for (int off = 32; off > 0; off >>= 1) {
    s  += __shfl_xor(s, off, 64);
    ss += __shfl_xor(ss, off, 64);
  }
  float mu  = s * (1.f / 512.f);
  float var = ss * (1.f / 512.f) - mu * mu;
  float rs  = rsqrtf(var + 1e-5f);
  f32x4 g0 = *(const f32x4*)(g + c0), bb0 = *(const f32x4*)(b + c0);
  f32x4 g1 = *(const f32x4*)(g + c1), bb1 = *(const f32x4*)(b + c1);
  s16x4 o0, o1;
#pragma unroll
  for (int e = 0; e < 4; ++e) {
    o0[e] = f2bf(fmaxf((v0[e] - mu) * rs * g0[e] + bb0[e], 0.f));
    o1[e] = f2bf(fmaxf((v1[e] - mu) * rs * g1[e] + bb1[e], 0.f));
  }
  *(s16x4*)(out + row * 512 + c0) = o0;
  *(s16x4*)(out + row * 512 + c1) = o1;
}

// ---------------------------------------------------------------------------
// Codebook prep: cbT[k][n] = codebook[n][k] (fp32), cbBias[n] = -0.5*||c_n||^2
// ---------------------------------------------------------------------------
__global__ __launch_bounds__(256)
void prep_cb_k(const float* __restrict__ cb, float* __restrict__ cbT,
               float* __restrict__ cbBias)
{
  __shared__ float red[256];
  const int r = blockIdx.x, tid = threadIdx.x;
  const float* row = cb + (long)r * 1024;
  float ss = 0.f;
  for (int c = tid; c < 1024; c += 256) {
    float v = row[c];
    cbT[(long)c * 256 + r] = v;
    ss += v * v;
  }
  red[tid] = ss; __syncthreads();
  for (int st = 128; st > 0; st >>= 1) {
    if (tid < st) red[tid] += red[tid + st];
    __syncthreads();
  }
  if (tid == 0) cbBias[r] = -0.5f * red[0];
}

// ---------------------------------------------------------------------------
// VQ: per-row argmax of scores (=f.c - .5||c||^2) + e_latent accumulation
// ---------------------------------------------------------------------------
__global__ __launch_bounds__(256)
void vq_k(const float* __restrict__ sc, const short* __restrict__ feat,
          int* __restrict__ idxp, float* __restrict__ e_acc)
{
  __shared__ float ep[4];
  const int wave = threadIdx.x >> 6, lane = threadIdx.x & 63;
  const long row = (long)blockIdx.x * 4 + wave;
  f32x4 s = *(const f32x4*)(sc + row * 256 + lane * 4);
  float best = s.x; int bi = lane * 4;
  if (s.y > best) { best = s.y; bi = lane * 4 + 1; }
  if (s.z > best) { best = s.z; bi = lane * 4 + 2; }
  if (s.w > best) { best = s.w; bi = lane * 4 + 3; }
#pragma unroll
  for (int off = 32; off > 0; off >>= 1) {
    float ov = __shfl_xor(best, off, 64);
    int   oi = __shfl_xor(bi, off, 64);
    if (ov > best || (ov == best && oi < bi)) { best = ov; bi = oi; }
  }
  const short* fr = feat + row * 1024;
  float sq = 0.f;
#pragma unroll
  for (int p = 0; p < 2; ++p) {
    s16x8 v = *(const s16x8*)(fr + p * 512 + lane * 8);
#pragma unroll
    for (int e = 0; e < 8; ++e) { float f = bf2f(v[e]); sq += f * f; }
  }
#pragma unroll
  for (int off = 32; off > 0; off >>= 1) sq += __shfl_xor(sq, off, 64);
  if (lane == 0) { idxp[row] = bi; ep[wave] = sq - 2.f * best; }
  __syncthreads();
  if (threadIdx.x == 0) atomicAdd(e_acc, ep[0] + ep[1] + ep[2] + ep[3]);
}

// ---------------------------------------------------------------------------
// Per-batch code histogram -> xm[b,:] = (hist/512) @ aligned_codes
// ---------------------------------------------------------------------------
__global__ __launch_bounds__(256)
void hist_xm_k(const int* __restrict__ idxp, const float* __restrict__ AC,
               float* __restrict__ xm)
{
  __shared__ int   hist[256];
  __shared__ float hf[256];
  const int b = blockIdx.x, tid = threadIdx.x;
  hist[tid] = 0; __syncthreads();
  for (int t = tid; t < 512; t += 256) atomicAdd(&hist[idxp[b * 512 + t]], 1);
  __syncthreads();
  hf[tid] = (float)hist[tid] * (1.f / 512.f);
  __syncthreads();
  for (int d = tid; d < 1024; d += 256) {
    float a = 0.f;
    for (int k = 0; k < 256; ++k) a += hf[k] * AC[(long)k * 1024 + d];
    xm[(long)b * 1024 + d] = a;
  }
}

// ---------------------------------------------------------------------------
// MMD: one block, 1024 threads = 32x32 pairs; xm staged in LDS (padded)
// ---------------------------------------------------------------------------
__global__ __launch_bounds__(1024)
void mmd_k(const float* __restrict__ xm, const float* __restrict__ prior,
           float* __restrict__ mmd_out)
{
  extern __shared__ float xs[];   // [32][1028]
  __shared__ float red[48];
  const int tid = threadIdx.x;
  for (int i = tid; i < 32 * 1024; i += 1024)
    xs[(i >> 10) * 1028 + (i & 1023)] = xm[i];
  __syncthreads();
  const int i = tid >> 5, j = tid & 31;
  const float* xi = xs + i * 1028;
  const float* xj = xs + j * 1028;
  const float* pi = prior + (long)i * 1024;
  const float* pj = prior + (long)j * 1024;
  float dxx = 0.f, dyy = 0.f, dxy = 0.f;
  for (int d = 0; d < 1024; d += 4) {
    f32x4 a = *(const f32x4*)(xi + d);
    f32x4 b = *(const f32x4*)(xj + d);
    f32x4 p = *(const f32x4*)(pi + d);
    f32x4 q = *(const f32x4*)(pj + d);
#pragma unroll
    for (int e = 0; e < 4; ++e) {
      float t1 = a[e] - b[e]; dxx += t1 * t1;
      float t2 = p[e] - q[e]; dyy += t2 * t2;
      float t3 = a[e] - q[e]; dxy += t3 * t3;
    }
  }
  float kxx = __expf(-dxx * (1.f / 1024.f));
  float kyy = __expf(-dyy * (1.f / 1024.f));
  float kxy = __expf(-dxy * (1.f / 1024.f));
  const int wv = tid >> 6, lane = tid & 63;
#pragma unroll
  for (int off = 32; off > 0; off >>= 1) {
    kxx += __shfl_xor(kxx, off, 64);
    kyy += __shfl_xor(kyy, off, 64);
    kxy += __shfl_xor(kxy, off, 64);
  }
  if (lane == 0) { red[wv] = kxx; red[16 + wv] = kyy; red[32 + wv] = kxy; }
  __syncthreads();
  if (tid == 0) {
    float sxx = 0.f, syy = 0.f, sxy = 0.f;
    for (int w = 0; w < 16; ++w) {
      sxx += red[w]; syy += red[16 + w]; sxy += red[32 + w];
    }
    mmd_out[0] = (sxx + syy - 2.f * sxy) * (1.f / 1024.f);
  }
}

// ---------------------------------------------------------------------------
// Persistent GRU, round 6. 64 WGs x 128 thr (1 WG/CU). WG g owns hidden dims
// [g*16, g*16+16). h lives IN ctx. READ: plain nontemporal b128 of virgin
// ctx[.,t-1,.] lines (cached path; XCD L2 multicasts to its 8 WGs). WRITE:
// per-wave LDS micro-transpose -> coalesced b128 sc1 stores to LLC. Per-wave
// epoch flags (relaxed agent atomics), no __syncthreads in loop.
// ---------------------------------------------------------------------------
__global__ __launch_bounds__(128, 1)
void gru_k(const float* __restrict__ Whh, const float* __restrict__ bhh,
           const float* __restrict__ cgx, const int* __restrict__ idxp,
           u32* __restrict__ ctxw, const short* __restrict__ ctxr,
           int* __restrict__ flags)
{
  extern __shared__ short Bsl[];   // [48][1034] weights + 2x[16][24] scratch
  short* scr = Bsl + 48 * 1034;
  const int tid = threadIdx.x, g = blockIdx.x;
  const int wave = tid >> 6, lane = tid & 63;
  const int l16 = lane & 15, quad = lane >> 4;

  // stage Whh slice: local col c = gate*16+dl -> global col gate*1024+g*16+dl
  for (int i = tid; i < 48 * 1024; i += 128) {
    int c = i % 48, k = i / 48;
    int gate = c >> 4, dl = c & 15;
    Bsl[c * 1034 + k] = f2bf(Whh[(long)k * 3072 + gate * 1024 + g * 16 + dl]);
  }
  const int dcol = g * 16 + l16;
  const float bhr = bhh[dcol], bhz = bhh[dcol + 1024], bhn = bhh[dcol + 2048];
  const short* b0 = &Bsl[l16 * 1034 + quad * 8];
  const short* b1 = b0 + 16 * 1034;
  const short* b2 = b0 + 32 * 1034;
  short* sw = scr + wave * 384;          // [16 rows][stride 24] bf16
  float hreg[4] = {0.f, 0.f, 0.f, 0.f};
  int brow[4];
#pragma unroll
  for (int r = 0; r < 4; ++r) brow[r] = wave * 16 + quad * 4 + r;
  const int myflag = g * 2 + wave;
  __syncthreads();   // Bsl staged by both waves

  // A-row base for this lane (m index = l16): ctx[(wave*16+l16), t-1, quad*8+]
  const long arow = ((long)(wave * 16 + l16) * 512) * 1024 + quad * 8;

  // preload gx for t=0 (cached; stays warm in L2)
  float xr[4], xz[4], xn[4];
#pragma unroll
  for (int r = 0; r < 4; ++r) {
    int code = idxp[brow[r] * 512];
    const float* gp = cgx + (long)code * 3072 + dcol;
    xr[r] = gp[0]; xz[r] = gp[1024]; xn[r] = gp[2048];
  }

  for (int t = 0; t < 512; ++t) {
    f32x4 ar_ = {0.f,0.f,0.f,0.f}, az = ar_, an = ar_;
    if (t > 0) {
      // wait until all 128 waves have published h for epoch t
      int a, b;
      do {
        a = __hip_atomic_load(&flags[lane],      __ATOMIC_RELAXED,
                              __HIP_MEMORY_SCOPE_AGENT);
        b = __hip_atomic_load(&flags[64 + lane], __ATOMIC_RELAXED,
                              __HIP_MEMORY_SCOPE_AGENT);
      } while (__any(a < t || b < t));
      asm volatile("" ::: "memory");   // no hoisting of h loads above poll
      // ---- all 32 A-tile loads in flight together (CACHED path, virgin
      //      lines -> L2 fill; correct because each line is read exactly
      //      once, strictly after its producer's flag) ----
      const short* ap = ctxr + arow + (long)(t - 1) * 1024;
      s16x8 A[32];
#pragma unroll
      for (int ks = 0; ks < 32; ++ks)
        A[ks] = __builtin_nontemporal_load((const s16x8*)(ap + ks * 32));
      asm volatile("" ::: "memory");
      // ---- gh = h_{t-1} @ Whh_slice (B streamed from LDS) ----
#pragma unroll
      for (int ks = 0; ks < 32; ++ks) {
        ar_ = mfma16(A[ks], *(const s16x8*)(b0 + ks * 32), ar_);
        az  = mfma16(A[ks], *(const s16x8*)(b1 + ks * 32), az);
        an  = mfma16(A[ks], *(const s16x8*)(b2 + ks * 32), an);
      }
    }
    // gates
#pragma unroll
    for (int r = 0; r < 4; ++r) {
      float rr = 1.f / (1.f + __expf(-(xr[r] + ar_[r] + bhr)));
      float zz = 1.f / (1.f + __expf(-(xz[r] + az[r] + bhz)));
      float u  = xn[r] + rr * (an[r] + bhn);
      float e  = __expf(-2.f * u);
      float nn = (1.f - e) / (1.f + e);
      hreg[r]  = (1.f - zz) * nn + zz * hreg[r];
    }
    // publish h_t: per-wave LDS transpose -> coalesced b128 sc1 stores
#pragma unroll
    for (int r = 0; r < 4; ++r)
      sw[(quad * 4 + r) * 24 + l16] = f2bf(hreg[r]);
    asm volatile("s_waitcnt lgkmcnt(0)" ::: "memory");
    __builtin_amdgcn_wave_barrier();
    if (lane < 32) {
      int row = lane >> 1, half = lane & 1;
      u32x4 v = *(const u32x4*)(sw + row * 24 + half * 8);
      int rg = wave * 16 + row;
      u32* dst = ctxw + ((long)rg * 512 + t) * 512 + g * 8 + half * 4;
      st_uc128(dst, v);
    }
    vm_drain();   // h stores acked at LLC
    if (lane == 0)
      __hip_atomic_store(&flags[myflag], t + 1, __ATOMIC_RELAXED,
                         __HIP_MEMORY_SCOPE_AGENT);
    // prefetch gx for t+1 AFTER the flag (hides under next step's poll)
    int tn = (t + 1 < 512) ? t + 1 : 0;
#pragma unroll
    for (int r = 0; r < 4; ++r) {
      int code = idxp[brow[r] * 512 + tn];
      const float* gp = cgx + (long)code * 3072 + dcol;
      xr[r] = gp[0]; xz[r] = gp[1024]; xn[r] = gp[2048];
    }
  }
}

// ---------------------------------------------------------------------------
__global__ void fin_k(const float* __restrict__ scal, float* __restrict__ out)
{
  float recon = scal[3] * (1.f / 16777216.f);
  float vq    = 1.25f * scal[2] * (1.f / 16777216.f);
  float mmd   = scal[4];
  out[0] = recon;
  out[1] = vq;
  out[2] = mmd;
  out[3] = recon + vq + 0.5f * mmd;
}

// ---------------------------------------------------------------------------
extern "C" void kernel_launch(void* const* d_in, const int* in_sizes, int n_in,
                              void* d_out, int out_size, void* d_ws, size_t ws_size,
                              hipStream_t stream)
{
  const float* x     = (const float*)d_in[0];
  const float* prior = (const float*)d_in[1];
  const float* encW1 = (const float*)d_in[2];
  const float* encb1 = (const float*)d_in[3];
  const float* lng   = (const float*)d_in[4];
  const float* lnb   = (const float*)d_in[5];
  const float* encW2 = (const float*)d_in[6];
  const float* encb2 = (const float*)d_in[7];
  const float* cb    = (const float*)d_in[8];
  const float* pW1   = (const float*)d_in[9];
  const float* pb1   = (const float*)d_in[10];
  const float* pW2   = (const float*)d_in[11];
  const float* pb2   = (const float*)d_in[12];
  const float* Wih   = (const float*)d_in[13];
  const float* Whh   = (const float*)d_in[14];
  const float* bih   = (const float*)d_in[15];
  const float* bhh   = (const float*)d_in[16];
  const float* headW = (const float*)d_in[17];
  const float* headb = (const float*)d_in[18];

  // workspace layout (total 89,654,528 B, same as previous rounds)
  char* ws = (char*)d_ws;
  if (ws_size < 89654528) return;
  float* h_pre  = (float*)(ws + 0);           // 32 MB (scores alias)
  float* scores = h_pre;
  int*   flags  = (int*)(ws + 131072);        // 512 B (after vq_k)
  short* h1     = (short*)(ws + 33554432);    // 16 MB
  short* feat   = (short*)(ws + 50331648);    // 32 MB (ctx alias after VQ)
  u32*   ctxw   = (u32*)feat;
  short* ctxr   = feat;
  float* cgx    = (float*)(ws + 83886080);    // 3 MB  code_gx = cb@Wih+bih
  float* AC     = (float*)(ws + 87031808);    // 1 MB  aligned codes
  float* cbT    = (float*)(ws + 88080384);    // 1 MB  codebook^T f32
  short* ch     = (short*)(ws + 89128960);    // 256 KB codes hidden (bf16)
  float* xm     = (float*)(ws + 89391104);    // 128 KB
  int*   idxp   = (int*)  (ws + 89522176);    // 64 KB
  float* scal   = (float*)(ws + 89653248);    // 256 B scalars
  float* e_acc  = scal + 2;
  float* r_acc  = scal + 3;
  float* mmdv   = scal + 4;
  float* cbBias = (float*)(ws + 89653504);    // 1 KB

  // zero loss accumulators (ws is poisoned 0xAA each launch)
  hipMemsetAsync(scal, 0, 256, stream);

  dim3 blk(256);
  prep_cb_k<<<256, blk, 0, stream>>>(cb, cbT, cbBias);
  // encoder layer 1: x @ W1 + b1 -> h_pre (f32)
  gemm_k<true, 0><<<dim3(128, 4), blk, 0, stream>>>(
      x, encW1, encb1, h_pre, nullptr, nullptr, 16384, 512, 1024);
  ln_relu_k<<<4096, blk, 0, stream>>>(h_pre, lng, lnb, h1);
  // encoder layer 2: h1 @ W2 + b2 -> feat (bf16)
  gemm_k<false, 1><<<dim3(128, 8), blk, 0, stream>>>(
      h1, encW2, encb2, feat, nullptr, nullptr, 16384, 1024, 512);
  // VQ scores: feat @ cbT - 0.5||c||^2 -> scores (f32, aliases h_pre)
  gemm_k<false, 0><<<dim3(128, 2), blk, 0, stream>>>(
      feat, cbT, cbBias, scores, nullptr, nullptr, 16384, 256, 1024);
  vq_k<<<4096, blk, 0, stream>>>(scores, feat, idxp, e_acc);
  // scores region dead -> flags live there (zeroed)
  hipMemsetAsync(flags, 0, 512, stream);
  // per-code tables: projector hidden (relu, bf16), aligned codes, gru gx
  gemm_k<true, 2><<<dim3(2, 4), blk, 0, stream>>>(
      cb, pW1, pb1, ch, nullptr, nullptr, 256, 512, 1024);
  gemm_k<false, 0><<<dim3(2, 8), blk, 0, stream>>>(
      ch, pW2, pb2, AC, nullptr, nullptr, 256, 1024, 512);
  gemm_k<true, 0><<<dim3(2, 24), blk, 0, stream>>>(
      cb, Wih, bih, cgx, nullptr, nullptr, 256, 3072, 1024);
  // MMD path
  hist_xm_k<<<32, blk, 0, stream>>>(idxp, AC, xm);
  mmd_k<<<1, 1024, 32 * 1028 * 4, stream>>>(xm, prior, mmdv);
  // persistent GRU (h exchanged through ctx: sc1 publish, cached virgin read)
  gru_k<<<64, 128, 48 * 1034 * 2 + 2 * 384 * 2, stream>>>(
      Whh, bhh, cgx, idxp, ctxw, ctxr, flags);
  // head GEMM + fused recon sq-err reduction
  gemm_k<false, 3><<<dim3(128, 8), blk, 0, stream>>>(
      ctxr, headW, headb, nullptr, x, r_acc, 16384, 1024, 1024);
  fin_k<<<1, 1, 0, stream>>>(scal, (float*)d_out);
}

// Round 7
// 5488.409 us; speedup vs baseline: 1.8397x; 1.0490x over previous
//
#include <hip/hip_runtime.h>

// ---------------------------------------------------------------------------
// SignLLM forward. Round 7: poll-storm decongestion. r1/r2/r4/r6 all pinned
// at 10.3us/step regardless of protocol/data path => the cost is sync-
// structural. Hypothesis: 128 waves spin-loading 512B of flags saturates the
// LLC banks; producer flag stores queue behind the storm (~9us). Fix: s_sleep
// backoff, 64 per-WG flags each on a private 128B line, only wave 0 polls.
// Publish/data paths byte-identical to r6 (b128 sc1 publish, cached virgin
// reads of ctx).
// ---------------------------------------------------------------------------

typedef __attribute__((ext_vector_type(4))) float  f32x4;
typedef __attribute__((ext_vector_type(8))) short  s16x8;
typedef __attribute__((ext_vector_type(4))) short  s16x4;
typedef __attribute__((ext_vector_type(8))) __bf16 bf16x8;
typedef __attribute__((ext_vector_type(4))) unsigned int u32x4;
typedef unsigned long long u64;
typedef unsigned int       u32;

__device__ __forceinline__ short f2bf(float f) {
  __bf16 h = (__bf16)f;
  return __builtin_bit_cast(short, h);
}
__device__ __forceinline__ float bf2f(short s) {
  return (float)__builtin_bit_cast(__bf16, s);
}
__device__ __forceinline__ f32x4 mfma16(s16x8 a, s16x8 b, f32x4 c) {
  return __builtin_amdgcn_mfma_f32_16x16x32_bf16(
      __builtin_bit_cast(bf16x8, a), __builtin_bit_cast(bf16x8, b), c, 0, 0, 0);
}
__device__ __forceinline__ void vm_drain() {
  asm volatile("s_waitcnt vmcnt(0)" ::: "memory");
}
// uncached 16B store straight to LLC (coherence point) — no L1/L2 allocate
__device__ __forceinline__ void st_uc128(u32* p, u32x4 v) {
  asm volatile("global_store_dwordx4 %0, %1, off sc0 sc1"
               :: "v"(p), "v"(v) : "memory");
}

// ---------------------------------------------------------------------------
// Generic bf16 MFMA GEMM: C[M,N] = A[M,K] @ B[K,N] + bias, tile 128x128, BK=64
// EPI: 0 = store f32, 1 = store bf16, 2 = relu+store bf16,
//      3 = no store; accumulate sum((C - Xref)^2) into accum (head loss)
// ---------------------------------------------------------------------------
template<bool AF32, int EPI>
__global__ __launch_bounds__(256)
void gemm_k(const void* __restrict__ Ap, const float* __restrict__ Bp,
            const float* __restrict__ bias, void* __restrict__ Cp,
            const float* __restrict__ Xref, float* __restrict__ accum,
            int M, int N, int K)
{
  __shared__ short As[128][72];   // row-major [m][k], padded
  __shared__ short Bs[128][72];   // col-major [n][k], padded
  const int tid  = threadIdx.x;
  const long bm  = (long)blockIdx.x * 128;
  const long bn  = (long)blockIdx.y * 128;
  const int wave = tid >> 6, lane = tid & 63;
  const int wm = (wave >> 1) * 64, wn = (wave & 1) * 64;
  const int l16 = lane & 15, quad = lane >> 4;

  f32x4 acc[4][4];
#pragma unroll
  for (int i = 0; i < 4; ++i)
#pragma unroll
    for (int j = 0; j < 4; ++j) acc[i][j] = (f32x4){0.f, 0.f, 0.f, 0.f};

  const int atc = tid & 15, atr = tid >> 4;   // A staging: 16 cols x 16 rows
  const int btc = tid & 31, btr = tid >> 5;   // B staging: 32 cols x 8 rows

  for (int kt = 0; kt < K; kt += 64) {
#pragma unroll
    for (int p = 0; p < 8; ++p) {
      int r = p * 16 + atr;
      if (AF32) {
        const float* src = (const float*)Ap + (bm + r) * (long)K + kt + atc * 4;
        f32x4 v = *(const f32x4*)src;
        s16x4 s;
        s.x = f2bf(v.x); s.y = f2bf(v.y); s.z = f2bf(v.z); s.w = f2bf(v.w);
        *(s16x4*)&As[r][atc * 4] = s;
      } else {
        const short* src = (const short*)Ap + (bm + r) * (long)K + kt + atc * 4;
        *(s16x4*)&As[r][atc * 4] = *(const s16x4*)src;
      }
    }
#pragma unroll
    for (int p = 0; p < 8; ++p) {
      int kk = p * 8 + btr;
      const float* brow = Bp + (long)(kt + kk) * N + bn + btc;
#pragma unroll
      for (int j = 0; j < 4; ++j) Bs[btc + 32 * j][kk] = f2bf(brow[32 * j]);
    }
    __syncthreads();
#pragma unroll
    for (int kk = 0; kk < 64; kk += 32) {
      s16x8 af[4], bf[4];
#pragma unroll
      for (int i = 0; i < 4; ++i)
        af[i] = *(const s16x8*)&As[wm + i * 16 + l16][kk + quad * 8];
#pragma unroll
      for (int j = 0; j < 4; ++j)
        bf[j] = *(const s16x8*)&Bs[wn + j * 16 + l16][kk + quad * 8];
#pragma unroll
      for (int i = 0; i < 4; ++i)
#pragma unroll
        for (int j = 0; j < 4; ++j) acc[i][j] = mfma16(af[i], bf[j], acc[i][j]);
    }
    __syncthreads();
  }

  if (EPI == 3) {
    float ls = 0.f;
#pragma unroll
    for (int i = 0; i < 4; ++i)
#pragma unroll
      for (int j = 0; j < 4; ++j) {
        long col = bn + wn + j * 16 + l16;
        float bv = bias[col];
#pragma unroll
        for (int r = 0; r < 4; ++r) {
          long row = bm + wm + i * 16 + quad * 4 + r;
          float v = acc[i][j][r] + bv;
          float d = v - Xref[row * N + col];
          ls += d * d;
        }
      }
#pragma unroll
    for (int off = 32; off > 0; off >>= 1) ls += __shfl_xor(ls, off, 64);
    if (lane == 0) atomicAdd(accum, ls);
  } else {
#pragma unroll
    for (int i = 0; i < 4; ++i)
#pragma unroll
      for (int j = 0; j < 4; ++j) {
        long col = bn + wn + j * 16 + l16;
        float bv = bias[col];
#pragma unroll
        for (int r = 0; r < 4; ++r) {
          long row = bm + wm + i * 16 + quad * 4 + r;
          float v = acc[i][j][r] + bv;
          if (EPI == 2) v = fmaxf(v, 0.f);
          if (EPI == 0) ((float*)Cp)[row * N + col] = v;
          else          ((short*)Cp)[row * N + col] = f2bf(v);
        }
      }
  }
}

// ---------------------------------------------------------------------------
// LayerNorm(512) + ReLU, fp32 in -> bf16 out. One wave per row.
// ---------------------------------------------------------------------------
__global__ __launch_bounds__(256)
void ln_relu_k(const float* __restrict__ hp, const float* __restrict__ g,
               const float* __restrict__ b, short* __restrict__ out)
{
  const int wave = threadIdx.x >> 6, lane = threadIdx.x & 63;
  const long row = (long)blockIdx.x * 4 + wave;
  const float* hr = hp + row * 512;
  const int c0 = lane * 4, c1 = 256 + lane * 4;
  f32x4 v0 = *(const f32x4*)(hr + c0);
  f32x4 v1 = *(const f32x4*)(hr + c1);
  float s  = v0.x + v0.y + v0.z + v0.w + v1.x + v1.y + v1.z + v1.w;
  float ss = v0.x*v0.x + v0.y*v0.y + v0.z*v0.z + v0.w*v0.w
           + v1.x*v1.x + v1.y*v1.y + v1.z*v1.z + v1.w*v1.w;
#pragma unroll
  for (int off = 32; off > 0; off >>= 1) {
    s  += __shfl_xor(s, off, 64);
    ss += __shfl_xor(ss, off, 64);
  }
  float mu  = s * (1.f / 512.f);
  float var = ss * (1.f / 512.f) - mu * mu;
  float rs  = rsqrtf(var + 1e-5f);
  f32x4 g0 = *(const f32x4*)(g + c0), bb0 = *(const f32x4*)(b + c0);
  f32x4 g1 = *(const f32x4*)(g + c1), bb1 = *(const f32x4*)(b + c1);
  s16x4 o0, o1;
#pragma unroll
  for (int e = 0; e < 4; ++e) {
    o0[e] = f2bf(fmaxf((v0[e] - mu) * rs * g0[e] + bb0[e], 0.f));
    o1[e] = f2bf(fmaxf((v1[e] - mu) * rs * g1[e] + bb1[e], 0.f));
  }
  *(s16x4*)(out + row * 512 + c0) = o0;
  *(s16x4*)(out + row * 512 + c1) = o1;
}

// ---------------------------------------------------------------------------
// Codebook prep: cbT[k][n] = codebook[n][k] (fp32), cbBias[n] = -0.5*||c_n||^2
// ---------------------------------------------------------------------------
__global__ __launch_bounds__(256)
void prep_cb_k(const float* __restrict__ cb, float* __restrict__ cbT,
               float* __restrict__ cbBias)
{
  __shared__ float red[256];
  const int r = blockIdx.x, tid = threadIdx.x;
  const float* row = cb + (long)r * 1024;
  float ss = 0.f;
  for (int c = tid; c < 1024; c += 256) {
    float v = row[c];
    cbT[(long)c * 256 + r] = v;
    ss += v * v;
  }
  red[tid] = ss; __syncthreads();
  for (int st = 128; st > 0; st >>= 1) {
    if (tid < st) red[tid] += red[tid + st];
    __syncthreads();
  }
  if (tid == 0) cbBias[r] = -0.5f * red[0];
}

// ---------------------------------------------------------------------------
// VQ: per-row argmax of scores (=f.c - .5||c||^2) + e_latent accumulation
// ---------------------------------------------------------------------------
__global__ __launch_bounds__(256)
void vq_k(const float* __restrict__ sc, const short* __restrict__ feat,
          int* __restrict__ idxp, float* __restrict__ e_acc)
{
  __shared__ float ep[4];
  const int wave = threadIdx.x >> 6, lane = threadIdx.x & 63;
  const long row = (long)blockIdx.x * 4 + wave;
  f32x4 s = *(const f32x4*)(sc + row * 256 + lane * 4);
  float best = s.x; int bi = lane * 4;
  if (s.y > best) { best = s.y; bi = lane * 4 + 1; }
  if (s.z > best) { best = s.z; bi = lane * 4 + 2; }
  if (s.w > best) { best = s.w; bi = lane * 4 + 3; }
#pragma unroll
  for (int off = 32; off > 0; off >>= 1) {
    float ov = __shfl_xor(best, off, 64);
    int   oi = __shfl_xor(bi, off, 64);
    if (ov > best || (ov == best && oi < bi)) { best = ov; bi = oi; }
  }
  const short* fr = feat + row * 1024;
  float sq = 0.f;
#pragma unroll
  for (int p = 0; p < 2; ++p) {
    s16x8 v = *(const s16x8*)(fr + p * 512 + lane * 8);
#pragma unroll
    for (int e = 0; e < 8; ++e) { float f = bf2f(v[e]); sq += f * f; }
  }
#pragma unroll
  for (int off = 32; off > 0; off >>= 1) sq += __shfl_xor(sq, off, 64);
  if (lane == 0) { idxp[row] = bi; ep[wave] = sq - 2.f * best; }
  __syncthreads();
  if (threadIdx.x == 0) atomicAdd(e_acc, ep[0] + ep[1] + ep[2] + ep[3]);
}

// ---------------------------------------------------------------------------
// Per-batch code histogram -> xm[b,:] = (hist/512) @ aligned_codes
// ---------------------------------------------------------------------------
__global__ __launch_bounds__(256)
void hist_xm_k(const int* __restrict__ idxp, const float* __restrict__ AC,
               float* __restrict__ xm)
{
  __shared__ int   hist[256];
  __shared__ float hf[256];
  const int b = blockIdx.x, tid = threadIdx.x;
  hist[tid] = 0; __syncthreads();
  for (int t = tid; t < 512; t += 256) atomicAdd(&hist[idxp[b * 512 + t]], 1);
  __syncthreads();
  hf[tid] = (float)hist[tid] * (1.f / 512.f);
  __syncthreads();
  for (int d = tid; d < 1024; d += 256) {
    float a = 0.f;
    for (int k = 0; k < 256; ++k) a += hf[k] * AC[(long)k * 1024 + d];
    xm[(long)b * 1024 + d] = a;
  }
}

// ---------------------------------------------------------------------------
// MMD: one block, 1024 threads = 32x32 pairs; xm staged in LDS (padded)
// ---------------------------------------------------------------------------
__global__ __launch_bounds__(1024)
void mmd_k(const float* __restrict__ xm, const float* __restrict__ prior,
           float* __restrict__ mmd_out)
{
  extern __shared__ float xs[];   // [32][1028]
  __shared__ float red[48];
  const int tid = threadIdx.x;
  for (int i = tid; i < 32 * 1024; i += 1024)
    xs[(i >> 10) * 1028 + (i & 1023)] = xm[i];
  __syncthreads();
  const int i = tid >> 5, j = tid & 31;
  const float* xi = xs + i * 1028;
  const float* xj = xs + j * 1028;
  const float* pi = prior + (long)i * 1024;
  const float* pj = prior + (long)j * 1024;
  float dxx = 0.f, dyy = 0.f, dxy = 0.f;
  for (int d = 0; d < 1024; d += 4) {
    f32x4 a = *(const f32x4*)(xi + d);
    f32x4 b = *(const f32x4*)(xj + d);
    f32x4 p = *(const f32x4*)(pi + d);
    f32x4 q = *(const f32x4*)(pj + d);
#pragma unroll
    for (int e = 0; e < 4; ++e) {
      float t1 = a[e] - b[e]; dxx += t1 * t1;
      float t2 = p[e] - q[e]; dyy += t2 * t2;
      float t3 = a[e] - q[e]; dxy += t3 * t3;
    }
  }
  float kxx = __expf(-dxx * (1.f / 1024.f));
  float kyy = __expf(-dyy * (1.f / 1024.f));
  float kxy = __expf(-dxy * (1.f / 1024.f));
  const int wv = tid >> 6, lane = tid & 63;
#pragma unroll
  for (int off = 32; off > 0; off >>= 1) {
    kxx += __shfl_xor(kxx, off, 64);
    kyy += __shfl_xor(kyy, off, 64);
    kxy += __shfl_xor(kxy, off, 64);
  }
  if (lane == 0) { red[wv] = kxx; red[16 + wv] = kyy; red[32 + wv] = kxy; }
  __syncthreads();
  if (tid == 0) {
    float sxx = 0.f, syy = 0.f, sxy = 0.f;
    for (int w = 0; w < 16; ++w) {
      sxx += red[w]; syy += red[16 + w]; sxy += red[32 + w];
    }
    mmd_out[0] = (sxx + syy - 2.f * sxy) * (1.f / 1024.f);
  }
}

// ---------------------------------------------------------------------------
// Persistent GRU, round 7. Data paths identical to r6. Sync decongested:
// - ONE flag per WG (64 total), each on a private 128-B line (stride 32 ints)
// - set by tid0 after BOTH waves' sc1 stores are LLC-acked (vm_drain +
//   __syncthreads)
// - polled ONLY by wave 0 (64 polling waves, 1 load/lane) with s_sleep(4)
//   backoff (~107ns) between attempts; wave 1 parks at __syncthreads.
// ---------------------------------------------------------------------------
__global__ __launch_bounds__(128, 1)
void gru_k(const float* __restrict__ Whh, const float* __restrict__ bhh,
           const float* __restrict__ cgx, const int* __restrict__ idxp,
           u32* __restrict__ ctxw, const short* __restrict__ ctxr,
           int* __restrict__ flags)
{
  extern __shared__ short Bsl[];   // [48][1034] weights + 2x[16][24] scratch
  short* scr = Bsl + 48 * 1034;
  const int tid = threadIdx.x, g = blockIdx.x;
  const int wave = tid >> 6, lane = tid & 63;
  const int l16 = lane & 15, quad = lane >> 4;

  // stage Whh slice: local col c = gate*16+dl -> global col gate*1024+g*16+dl
  for (int i = tid; i < 48 * 1024; i += 128) {
    int c = i % 48, k = i / 48;
    int gate = c >> 4, dl = c & 15;
    Bsl[c * 1034 + k] = f2bf(Whh[(long)k * 3072 + gate * 1024 + g * 16 + dl]);
  }
  const int dcol = g * 16 + l16;
  const float bhr = bhh[dcol], bhz = bhh[dcol + 1024], bhn = bhh[dcol + 2048];
  const short* b0 = &Bsl[l16 * 1034 + quad * 8];
  const short* b1 = b0 + 16 * 1034;
  const short* b2 = b0 + 32 * 1034;
  short* sw = scr + wave * 384;          // [16 rows][stride 24] bf16
  float hreg[4] = {0.f, 0.f, 0.f, 0.f};
  int brow[4];
#pragma unroll
  for (int r = 0; r < 4; ++r) brow[r] = wave * 16 + quad * 4 + r;
  __syncthreads();   // Bsl staged by both waves

  // A-row base for this lane (m index = l16): ctx[(wave*16+l16), t-1, quad*8+]
  const long arow = ((long)(wave * 16 + l16) * 512) * 1024 + quad * 8;

  // preload gx for t=0 (cached; stays warm in L2)
  float xr[4], xz[4], xn[4];
#pragma unroll
  for (int r = 0; r < 4; ++r) {
    int code = idxp[brow[r] * 512];
    const float* gp = cgx + (long)code * 3072 + dcol;
    xr[r] = gp[0]; xz[r] = gp[1024]; xn[r] = gp[2048];
  }

  for (int t = 0; t < 512; ++t) {
    f32x4 ar_ = {0.f,0.f,0.f,0.f}, az = ar_, an = ar_;
    if (t > 0) {
      // wave 0 polls the 64 per-WG flags (1 per lane, each on its own line)
      if (wave == 0) {
        for (;;) {
          int a = __hip_atomic_load(&flags[lane * 32], __ATOMIC_RELAXED,
                                    __HIP_MEMORY_SCOPE_AGENT);
          if (!__any(a < t)) break;
          __builtin_amdgcn_s_sleep(4);   // ~107ns backoff: kill the storm
        }
      }
      __syncthreads();                   // release wave 1
      asm volatile("" ::: "memory");
      // all 32 A-tile loads in flight together (cached path, virgin lines)
      const short* ap = ctxr + arow + (long)(t - 1) * 1024;
      s16x8 A[32];
#pragma unroll
      for (int ks = 0; ks < 32; ++ks)
        A[ks] = __builtin_nontemporal_load((const s16x8*)(ap + ks * 32));
      asm volatile("" ::: "memory");
      // gh = h_{t-1} @ Whh_slice (B streamed from LDS)
#pragma unroll
      for (int ks = 0; ks < 32; ++ks) {
        ar_ = mfma16(A[ks], *(const s16x8*)(b0 + ks * 32), ar_);
        az  = mfma16(A[ks], *(const s16x8*)(b1 + ks * 32), az);
        an  = mfma16(A[ks], *(const s16x8*)(b2 + ks * 32), an);
      }
    }
    // gates
#pragma unroll
    for (int r = 0; r < 4; ++r) {
      float rr = 1.f / (1.f + __expf(-(xr[r] + ar_[r] + bhr)));
      float zz = 1.f / (1.f + __expf(-(xz[r] + az[r] + bhz)));
      float u  = xn[r] + rr * (an[r] + bhn);
      float e  = __expf(-2.f * u);
      float nn = (1.f - e) / (1.f + e);
      hreg[r]  = (1.f - zz) * nn + zz * hreg[r];
    }
    // publish h_t: per-wave LDS transpose -> coalesced b128 sc1 stores
#pragma unroll
    for (int r = 0; r < 4; ++r)
      sw[(quad * 4 + r) * 24 + l16] = f2bf(hreg[r]);
    asm volatile("s_waitcnt lgkmcnt(0)" ::: "memory");
    __builtin_amdgcn_wave_barrier();
    if (lane < 32) {
      int row = lane >> 1, half = lane & 1;
      u32x4 v = *(const u32x4*)(sw + row * 24 + half * 8);
      int rg = wave * 16 + row;
      u32* dst = ctxw + ((long)rg * 512 + t) * 512 + g * 8 + half * 4;
      st_uc128(dst, v);
    }
    vm_drain();        // this wave's h stores acked at LLC
    __syncthreads();   // both waves drained
    if (tid == 0)
      __hip_atomic_store(&flags[g * 32], t + 1, __ATOMIC_RELAXED,
                         __HIP_MEMORY_SCOPE_AGENT);
    // prefetch gx for t+1 (hides under next step's poll)
    int tn = (t + 1 < 512) ? t + 1 : 0;
#pragma unroll
    for (int r = 0; r < 4; ++r) {
      int code = idxp[brow[r] * 512 + tn];
      const float* gp = cgx + (long)code * 3072 + dcol;
      xr[r] = gp[0]; xz[r] = gp[1024]; xn[r] = gp[2048];
    }
  }
}

// ---------------------------------------------------------------------------
__global__ void fin_k(const float* __restrict__ scal, float* __restrict__ out)
{
  float recon = scal[3] * (1.f / 16777216.f);
  float vq    = 1.25f * scal[2] * (1.f / 16777216.f);
  float mmd   = scal[4];
  out[0] = recon;
  out[1] = vq;
  out[2] = mmd;
  out[3] = recon + vq + 0.5f * mmd;
}

// ---------------------------------------------------------------------------
extern "C" void kernel_launch(void* const* d_in, const int* in_sizes, int n_in,
                              void* d_out, int out_size, void* d_ws, size_t ws_size,
                              hipStream_t stream)
{
  const float* x     = (const float*)d_in[0];
  const float* prior = (const float*)d_in[1];
  const float* encW1 = (const float*)d_in[2];
  const float* encb1 = (const float*)d_in[3];
  const float* lng   = (const float*)d_in[4];
  const float* lnb   = (const float*)d_in[5];
  const float* encW2 = (const float*)d_in[6];
  const float* encb2 = (const float*)d_in[7];
  const float* cb    = (const float*)d_in[8];
  const float* pW1   = (const float*)d_in[9];
  const float* pb1   = (const float*)d_in[10];
  const float* pW2   = (const float*)d_in[11];
  const float* pb2   = (const float*)d_in[12];
  const float* Wih   = (const float*)d_in[13];
  const float* Whh   = (const float*)d_in[14];
  const float* bih   = (const float*)d_in[15];
  const float* bhh   = (const float*)d_in[16];
  const float* headW = (const float*)d_in[17];
  const float* headb = (const float*)d_in[18];

  // workspace layout (total 89,654,528 B, same as previous rounds)
  char* ws = (char*)d_ws;
  if (ws_size < 89654528) return;
  float* h_pre  = (float*)(ws + 0);           // 32 MB (scores alias)
  float* scores = h_pre;
  int*   flags  = (int*)(ws + 131072);        // 8 KB (after vq_k): 64x128B
  short* h1     = (short*)(ws + 33554432);    // 16 MB
  short* feat   = (short*)(ws + 50331648);    // 32 MB (ctx alias after VQ)
  u32*   ctxw   = (u32*)feat;
  short* ctxr   = feat;
  float* cgx    = (float*)(ws + 83886080);    // 3 MB  code_gx = cb@Wih+bih
  float* AC     = (float*)(ws + 87031808);    // 1 MB  aligned codes
  float* cbT    = (float*)(ws + 88080384);    // 1 MB  codebook^T f32
  short* ch     = (short*)(ws + 89128960);    // 256 KB codes hidden (bf16)
  float* xm     = (float*)(ws + 89391104);    // 128 KB
  int*   idxp   = (int*)  (ws + 89522176);    // 64 KB
  float* scal   = (float*)(ws + 89653248);    // 256 B scalars
  float* e_acc  = scal + 2;
  float* r_acc  = scal + 3;
  float* mmdv   = scal + 4;
  float* cbBias = (float*)(ws + 89653504);    // 1 KB

  // zero loss accumulators (ws is poisoned 0xAA each launch)
  hipMemsetAsync(scal, 0, 256, stream);

  dim3 blk(256);
  prep_cb_k<<<256, blk, 0, stream>>>(cb, cbT, cbBias);
  // encoder layer 1: x @ W1 + b1 -> h_pre (f32)
  gemm_k<true, 0><<<dim3(128, 4), blk, 0, stream>>>(
      x, encW1, encb1, h_pre, nullptr, nullptr, 16384, 512, 1024);
  ln_relu_k<<<4096, blk, 0, stream>>>(h_pre, lng, lnb, h1);
  // encoder layer 2: h1 @ W2 + b2 -> feat (bf16)
  gemm_k<false, 1><<<dim3(128, 8), blk, 0, stream>>>(
      h1, encW2, encb2, feat, nullptr, nullptr, 16384, 1024, 512);
  // VQ scores: feat @ cbT - 0.5||c||^2 -> scores (f32, aliases h_pre)
  gemm_k<false, 0><<<dim3(128, 2), blk, 0, stream>>>(
      feat, cbT, cbBias, scores, nullptr, nullptr, 16384, 256, 1024);
  vq_k<<<4096, blk, 0, stream>>>(scores, feat, idxp, e_acc);
  // scores region dead -> flags live there (zeroed; one per 128-B line)
  hipMemsetAsync(flags, 0, 8192, stream);
  // per-code tables: projector hidden (relu, bf16), aligned codes, gru gx
  gemm_k<true, 2><<<dim3(2, 4), blk, 0, stream>>>(
      cb, pW1, pb1, ch, nullptr, nullptr, 256, 512, 1024);
  gemm_k<false, 0><<<dim3(2, 8), blk, 0, stream>>>(
      ch, pW2, pb2, AC, nullptr, nullptr, 256, 1024, 512);
  gemm_k<true, 0><<<dim3(2, 24), blk, 0, stream>>>(
      cb, Wih, bih, cgx, nullptr, nullptr, 256, 3072, 1024);
  // MMD path
  hist_xm_k<<<32, blk, 0, stream>>>(idxp, AC, xm);
  mmd_k<<<1, 1024, 32 * 1028 * 4, stream>>>(xm, prior, mmdv);
  // persistent GRU (h exchanged through ctx: sc1 publish, cached virgin read)
  gru_k<<<64, 128, 48 * 1034 * 2 + 2 * 384 * 2, stream>>>(
      Whh, bhh, cgx, idxp, ctxw, ctxr, flags);
  // head GEMM + fused recon sq-err reduction
  gemm_k<false, 3><<<dim3(128, 8), blk, 0, stream>>>(
      ctxr, headW, headb, nullptr, x, r_acc, 16384, 1024, 1024);
  fin_k<<<1, 1, 0, stream>>>(scal, (float*)d_out);
}